// Round 2
// baseline (690.125 us; speedup 1.0000x reference)
//
#include <hip/hip_runtime.h>
#include <hip/hip_bf16.h>
#include <stdint.h>

// SparseMOE: N=8192 tokens, D_in=D_out=2048, E=8, top-2.
// Strategy: fp32 gating (exact top-2) + sparse bf16 MFMA grouped-GEMM over
// per-expert token lists; weighted atomicAdd combine into zeroed fp32 out.

#define N_TOK 8192
#define D_IN  2048
#define D_OUT 2048
#define NEXP  8

typedef __attribute__((ext_vector_type(8))) short s16x8;   // 8 x bf16
typedef __attribute__((ext_vector_type(4))) float f32x4;

__device__ inline unsigned short f2b(float f) {
  union { float f; unsigned u; } v; v.f = f;
  unsigned u = v.u;
  return (unsigned short)((u + 0x7fffu + ((u >> 16) & 1u)) >> 16);  // RNE
}

__device__ inline void glds16(const void* g, void* l) {
  __builtin_amdgcn_global_load_lds(
      (const __attribute__((address_space(1))) unsigned int*)g,
      (__attribute__((address_space(3))) unsigned int*)l,
      16, 0, 0);
}

// ---------------------------------------------------------------------------
// Kernel 1: gating (fp32, exact) + x -> bf16 conversion + routing lists.
// One wave per token; 2048 blocks x 256 threads.
// ---------------------------------------------------------------------------
__global__ __launch_bounds__(256)
void gate_kernel(const float* __restrict__ x, const float* __restrict__ Wg,
                 const float* __restrict__ bg, unsigned short* __restrict__ xb,
                 int* __restrict__ tokl, float* __restrict__ wl,
                 int* __restrict__ cursor) {
  const int wave = threadIdx.x >> 6, lane = threadIdx.x & 63;
  const int t = blockIdx.x * 4 + wave;
  const float4* __restrict__ xv = (const float4*)(x + (size_t)t * D_IN);
  ushort4* __restrict__ xo = (ushort4*)(xb + (size_t)t * D_IN);
  float s[NEXP] = {0.f, 0.f, 0.f, 0.f, 0.f, 0.f, 0.f, 0.f};
#pragma unroll
  for (int i = 0; i < D_IN / 256; ++i) {  // 8 float4 per lane
    float4 v = xv[i * 64 + lane];
    ushort4 o;
    o.x = f2b(v.x); o.y = f2b(v.y); o.z = f2b(v.z); o.w = f2b(v.w);
    xo[i * 64 + lane] = o;
    const int p = (i * 64 + lane) * 4;
    const float fv[4] = {v.x, v.y, v.z, v.w};
#pragma unroll
    for (int j = 0; j < 4; ++j) {
      const float4* wrow = (const float4*)(Wg + (size_t)(p + j) * NEXP);
      float4 w0 = wrow[0], w1 = wrow[1];
      s[0] += fv[j] * w0.x; s[1] += fv[j] * w0.y;
      s[2] += fv[j] * w0.z; s[3] += fv[j] * w0.w;
      s[4] += fv[j] * w1.x; s[5] += fv[j] * w1.y;
      s[6] += fv[j] * w1.z; s[7] += fv[j] * w1.w;
    }
  }
#pragma unroll
  for (int off = 32; off > 0; off >>= 1)
#pragma unroll
    for (int e = 0; e < NEXP; ++e) s[e] += __shfl_xor(s[e], off);

  if (lane == 0) {
    float v[NEXP];
#pragma unroll
    for (int e = 0; e < NEXP; ++e) v[e] = s[e] + bg[e];
    int i0 = 0; float b0 = v[0];
#pragma unroll
    for (int e = 1; e < NEXP; ++e) if (v[e] > b0) { b0 = v[e]; i0 = e; }
    int i1 = -1; float b1 = -3.4e38f;
#pragma unroll
    for (int e = 0; e < NEXP; ++e)
      if (e != i0 && v[e] > b1) { b1 = v[e]; i1 = e; }
    float e1 = expf(b1 - b0);        // <= 1
    float inv = 1.f / (1.f + e1);
    float w0 = inv, w1 = e1 * inv;   // softmax over the two kept logits
    int p0 = atomicAdd(&cursor[i0], 1);
    tokl[i0 * N_TOK + p0] = t; wl[i0 * N_TOK + p0] = w0;
    int p1 = atomicAdd(&cursor[i1], 1);
    tokl[i1 * N_TOK + p1] = t; wl[i1 * N_TOK + p1] = w1;
  }
}

// ---------------------------------------------------------------------------
// Kernel 2: We fp32 [E][K][N] -> bf16 transposed [E][N][K] (B^T layout so the
// GEMM's B fragments are k-contiguous). 64x64 tiles via padded LDS.
// ---------------------------------------------------------------------------
__global__ __launch_bounds__(256)
void wconv_kernel(const float* __restrict__ We, unsigned short* __restrict__ Web) {
  __shared__ unsigned short tile[64][68];  // pad: row stride 136 B (8B-aligned)
  const int b = blockIdx.x;
  const int e = b >> 10, r = (b >> 5) & 31, c = b & 31;  // r: K-tile, c: N-tile
  const int tr = threadIdx.x >> 4, tc = threadIdx.x & 15;
  const float* src = We + ((size_t)e * 2048 + (size_t)r * 64) * 2048 + (size_t)c * 64;
#pragma unroll
  for (int i = 0; i < 4; ++i) {
    int row = tr + i * 16;  // d_local
    float4 v = *(const float4*)(src + (size_t)row * 2048 + tc * 4);
    tile[tc * 4 + 0][row] = f2b(v.x);
    tile[tc * 4 + 1][row] = f2b(v.y);
    tile[tc * 4 + 2][row] = f2b(v.z);
    tile[tc * 4 + 3][row] = f2b(v.w);
  }
  __syncthreads();
  unsigned short* dst = Web + ((size_t)e * 2048 + (size_t)c * 64) * 2048 + (size_t)r * 64;
#pragma unroll
  for (int i = 0; i < 4; ++i) {
    int row = tr + i * 16;  // f_local
    ushort4 o;
    o.x = tile[row][tc * 4 + 0]; o.y = tile[row][tc * 4 + 1];
    o.z = tile[row][tc * 4 + 2]; o.w = tile[row][tc * 4 + 3];
    *(ushort4*)(dst + (size_t)row * 2048 + tc * 4) = o;
  }
}

// ---------------------------------------------------------------------------
// Kernel 3: grouped expert GEMM. 128x128 tile, BK=32, 4 waves (2x2), each wave
// 4x4 frags of mfma_f32_16x16x32_bf16. global_load_lds staging; A rows are
// gathered via per-lane token addresses (global src is per-lane; LDS linear).
// Epilogue: out[tok] += w * (acc + bias) via atomicAdd (out pre-zeroed).
// ---------------------------------------------------------------------------
__global__ __launch_bounds__(256, 2)
void moe_gemm(const unsigned short* __restrict__ xb,
              const unsigned short* __restrict__ Web,
              const float* __restrict__ be, const int* __restrict__ tokl,
              const float* __restrict__ wl, const int* __restrict__ cursor,
              float* __restrict__ out) {
  __shared__ __align__(16) unsigned short As[128][32];
  __shared__ __align__(16) unsigned short Bs[128][32];  // [f][d] (B^T)
  const int bid = blockIdx.x;
  const int e  = bid >> 10;
  const int mt = (bid >> 4) & 63;
  const int nt = bid & 15;
  const int M = cursor[e];
  if (mt * 128 >= M) return;

  const int w = threadIdx.x >> 6, lane = threadIdx.x & 63;
  const int wr = w >> 1, wc = w & 1;

  // Staging geometry: wave w covers rows [w*32, w*32+32) of both tiles,
  // 2 glds16 each for A and B; lane l covers row +(l>>2), cols (l&3)*8..+8.
  const int rs = w * 32 + (lane >> 2);
  const int cb = (lane & 3) * 8;
  int g0 = mt * 128 + rs;      if (g0 >= M) g0 = M - 1;
  int g1 = mt * 128 + rs + 16; if (g1 >= M) g1 = M - 1;
  const unsigned short* srcA0 = xb + (size_t)tokl[e * N_TOK + g0] * D_IN + cb;
  const unsigned short* srcA1 = xb + (size_t)tokl[e * N_TOK + g1] * D_IN + cb;
  const unsigned short* srcB0 = Web + ((size_t)e * D_OUT + nt * 128 + rs) * D_IN + cb;
  const unsigned short* srcB1 = srcB0 + (size_t)16 * D_IN;
  unsigned short* ldsA0 = &As[w * 32][0];
  unsigned short* ldsA1 = &As[w * 32 + 16][0];
  unsigned short* ldsB0 = &Bs[w * 32][0];
  unsigned short* ldsB1 = &Bs[w * 32 + 16][0];

  f32x4 acc[4][4];
#pragma unroll
  for (int m = 0; m < 4; ++m)
#pragma unroll
    for (int n = 0; n < 4; ++n) acc[m][n] = (f32x4){0.f, 0.f, 0.f, 0.f};

  const int lrow = lane & 15, lk = (lane >> 4) * 8;
  const unsigned short* pA = &As[wr * 64 + lrow][lk];
  const unsigned short* pB = &Bs[wc * 64 + lrow][lk];

  for (int kk = 0; kk < D_IN / 32; ++kk) {
    glds16(srcA0 + kk * 32, ldsA0);
    glds16(srcA1 + kk * 32, ldsA1);
    glds16(srcB0 + kk * 32, ldsB0);
    glds16(srcB1 + kk * 32, ldsB1);
    __syncthreads();  // drains vmcnt -> staging visible
    s16x8 a[4], b[4];
#pragma unroll
    for (int m = 0; m < 4; ++m) a[m] = *(const s16x8*)(pA + m * 16 * 32);
#pragma unroll
    for (int n = 0; n < 4; ++n) b[n] = *(const s16x8*)(pB + n * 16 * 32);
#pragma unroll
    for (int m = 0; m < 4; ++m)
#pragma unroll
      for (int n = 0; n < 4; ++n)
        acc[m][n] = __builtin_amdgcn_mfma_f32_16x16x32_bf16(a[m], b[n], acc[m][n], 0, 0, 0);
    __syncthreads();  // all waves done reading before next overwrite
  }

  // Epilogue: C/D layout col=lane&15, row=(lane>>4)*4+q (m89-verified).
  const int colbase = nt * 128 + wc * 64 + lrow;
  float biasv[4];
#pragma unroll
  for (int n = 0; n < 4; ++n) biasv[n] = be[e * D_OUT + colbase + n * 16];
  const int rbase = mt * 128 + wr * 64 + ((lane >> 4) << 2);
#pragma unroll
  for (int m = 0; m < 4; ++m) {
#pragma unroll
    for (int q = 0; q < 4; ++q) {
      int r = rbase + m * 16 + q;
      if (r < M) {
        int tok = tokl[e * N_TOK + r];
        float wgt = wl[e * N_TOK + r];
        float* orow = out + (size_t)tok * D_OUT + colbase;
#pragma unroll
        for (int n = 0; n < 4; ++n)
          atomicAdd(orow + n * 16, wgt * (acc[m][n][q] + biasv[n]));
      }
    }
  }
}

// ---------------------------------------------------------------------------
extern "C" void kernel_launch(void* const* d_in, const int* in_sizes, int n_in,
                              void* d_out, int out_size, void* d_ws, size_t ws_size,
                              hipStream_t stream) {
  const float* x  = (const float*)d_in[0];
  const float* We = (const float*)d_in[1];
  const float* be = (const float*)d_in[2];
  const float* Wg = (const float*)d_in[3];
  const float* bg = (const float*)d_in[4];
  float* out = (float*)d_out;

  char* ws = (char*)d_ws;
  unsigned short* xb  = (unsigned short*)ws;                            // 32 MiB
  unsigned short* Web = (unsigned short*)(ws + (size_t)N_TOK * D_IN * 2); // 64 MiB
  char* meta = ws + (size_t)N_TOK * D_IN * 2 + (size_t)NEXP * D_IN * D_OUT * 2;
  int*   tokl   = (int*)meta;                                  // 256 KiB
  float* wl     = (float*)(meta + (size_t)NEXP * N_TOK * 4);   // 256 KiB
  int*   cursor = (int*)(meta + 2 * (size_t)NEXP * N_TOK * 4); // 32 B

  hipMemsetAsync(cursor, 0, NEXP * sizeof(int), stream);
  hipMemsetAsync(d_out, 0, (size_t)N_TOK * D_OUT * sizeof(float), stream);
  gate_kernel<<<N_TOK / 4, 256, 0, stream>>>(x, Wg, bg, xb, tokl, wl, cursor);
  wconv_kernel<<<NEXP * 32 * 32, 256, 0, stream>>>(We, Web);
  moe_gemm<<<NEXP * 64 * 16, 256, 0, stream>>>(xb, Web, be, tokl, wl, cursor, out);
}

// Round 3
// 571.677 us; speedup vs baseline: 1.2072x; 1.2072x over previous
//
#include <hip/hip_runtime.h>
#include <hip/hip_bf16.h>
#include <stdint.h>

// SparseMOE: N=8192 tokens, D_in=D_out=2048, E=8, top-2.
// R3: fix routing-cursor atomic contention (16384 same-line atomics -> 4096
// block-aggregated atomics over 8 padded lines). GEMM unchanged for clean
// attribution.

#define N_TOK 8192
#define D_IN  2048
#define D_OUT 2048
#define NEXP  8
#define CURS_STRIDE 16  // ints; pads each expert cursor to its own 64B line

typedef __attribute__((ext_vector_type(8))) short s16x8;   // 8 x bf16
typedef __attribute__((ext_vector_type(4))) float f32x4;

__device__ inline unsigned short f2b(float f) {
  union { float f; unsigned u; } v; v.f = f;
  unsigned u = v.u;
  return (unsigned short)((u + 0x7fffu + ((u >> 16) & 1u)) >> 16);  // RNE
}

__device__ inline void glds16(const void* g, void* l) {
  __builtin_amdgcn_global_load_lds(
      (const __attribute__((address_space(1))) unsigned int*)g,
      (__attribute__((address_space(3))) unsigned int*)l,
      16, 0, 0);
}

// ---------------------------------------------------------------------------
// Kernel 1: gating (fp32, exact) + x -> bf16 conversion + routing lists.
// 1024 threads = 16 waves = 16 tokens per block; routing aggregated in LDS,
// one atomicAdd per (block, expert) on a padded cursor line.
// ---------------------------------------------------------------------------
__global__ __launch_bounds__(1024)
void gate_kernel(const float* __restrict__ x, const float* __restrict__ Wg,
                 const float* __restrict__ bg, unsigned short* __restrict__ xb,
                 int* __restrict__ tokl, float* __restrict__ wl,
                 int* __restrict__ cursor) {
  __shared__ int   s_i0[16], s_i1[16];
  __shared__ float s_w0[16], s_w1[16];
  const int wave = threadIdx.x >> 6, lane = threadIdx.x & 63;
  const int t = blockIdx.x * 16 + wave;
  const float4* __restrict__ xv = (const float4*)(x + (size_t)t * D_IN);
  ushort4* __restrict__ xo = (ushort4*)(xb + (size_t)t * D_IN);
  float s[NEXP] = {0.f, 0.f, 0.f, 0.f, 0.f, 0.f, 0.f, 0.f};
#pragma unroll
  for (int i = 0; i < D_IN / 256; ++i) {  // 8 float4 per lane
    float4 v = xv[i * 64 + lane];
    ushort4 o;
    o.x = f2b(v.x); o.y = f2b(v.y); o.z = f2b(v.z); o.w = f2b(v.w);
    xo[i * 64 + lane] = o;
    const int p = (i * 64 + lane) * 4;
    const float fv[4] = {v.x, v.y, v.z, v.w};
#pragma unroll
    for (int j = 0; j < 4; ++j) {
      const float4* wrow = (const float4*)(Wg + (size_t)(p + j) * NEXP);
      float4 w0 = wrow[0], w1 = wrow[1];
      s[0] += fv[j] * w0.x; s[1] += fv[j] * w0.y;
      s[2] += fv[j] * w0.z; s[3] += fv[j] * w0.w;
      s[4] += fv[j] * w1.x; s[5] += fv[j] * w1.y;
      s[6] += fv[j] * w1.z; s[7] += fv[j] * w1.w;
    }
  }
#pragma unroll
  for (int off = 32; off > 0; off >>= 1)
#pragma unroll
    for (int e = 0; e < NEXP; ++e) s[e] += __shfl_xor(s[e], off);

  if (lane == 0) {
    float v[NEXP];
#pragma unroll
    for (int e = 0; e < NEXP; ++e) v[e] = s[e] + bg[e];
    int i0 = 0; float b0 = v[0];
#pragma unroll
    for (int e = 1; e < NEXP; ++e) if (v[e] > b0) { b0 = v[e]; i0 = e; }
    int i1 = -1; float b1 = -3.4e38f;
#pragma unroll
    for (int e = 0; e < NEXP; ++e)
      if (e != i0 && v[e] > b1) { b1 = v[e]; i1 = e; }
    float e1 = expf(b1 - b0);        // <= 1
    float inv = 1.f / (1.f + e1);
    s_i0[wave] = i0; s_w0[wave] = inv;        // top-1 softmax weight
    s_i1[wave] = i1; s_w1[wave] = e1 * inv;   // top-2 softmax weight
  }
  __syncthreads();
  // Threads 0..7: one expert each. Count, reserve once, place entries.
  if (threadIdx.x < NEXP) {
    const int e = threadIdx.x;
    int cnt = 0;
#pragma unroll
    for (int j = 0; j < 16; ++j) cnt += (s_i0[j] == e) + (s_i1[j] == e);
    if (cnt > 0) {
      int base = atomicAdd(&cursor[e * CURS_STRIDE], cnt);
#pragma unroll
      for (int j = 0; j < 16; ++j) {
        int tok = blockIdx.x * 16 + j;
        if (s_i0[j] == e) { tokl[e * N_TOK + base] = tok; wl[e * N_TOK + base] = s_w0[j]; ++base; }
        if (s_i1[j] == e) { tokl[e * N_TOK + base] = tok; wl[e * N_TOK + base] = s_w1[j]; ++base; }
      }
    }
  }
}

// ---------------------------------------------------------------------------
// Kernel 2: We fp32 [E][K][N] -> bf16 transposed [E][N][K] (B^T layout so the
// GEMM's B fragments are k-contiguous). 64x64 tiles via padded LDS.
// ---------------------------------------------------------------------------
__global__ __launch_bounds__(256)
void wconv_kernel(const float* __restrict__ We, unsigned short* __restrict__ Web) {
  __shared__ unsigned short tile[64][68];  // pad: row stride 136 B (8B-aligned)
  const int b = blockIdx.x;
  const int e = b >> 10, r = (b >> 5) & 31, c = b & 31;  // r: K-tile, c: N-tile
  const int tr = threadIdx.x >> 4, tc = threadIdx.x & 15;
  const float* src = We + ((size_t)e * 2048 + (size_t)r * 64) * 2048 + (size_t)c * 64;
#pragma unroll
  for (int i = 0; i < 4; ++i) {
    int row = tr + i * 16;  // d_local
    float4 v = *(const float4*)(src + (size_t)row * 2048 + tc * 4);
    tile[tc * 4 + 0][row] = f2b(v.x);
    tile[tc * 4 + 1][row] = f2b(v.y);
    tile[tc * 4 + 2][row] = f2b(v.z);
    tile[tc * 4 + 3][row] = f2b(v.w);
  }
  __syncthreads();
  unsigned short* dst = Web + ((size_t)e * 2048 + (size_t)c * 64) * 2048 + (size_t)r * 64;
#pragma unroll
  for (int i = 0; i < 4; ++i) {
    int row = tr + i * 16;  // f_local
    ushort4 o;
    o.x = tile[row][tc * 4 + 0]; o.y = tile[row][tc * 4 + 1];
    o.z = tile[row][tc * 4 + 2]; o.w = tile[row][tc * 4 + 3];
    *(ushort4*)(dst + (size_t)row * 2048 + tc * 4) = o;
  }
}

// ---------------------------------------------------------------------------
// Kernel 3: grouped expert GEMM. 128x128 tile, BK=32, 4 waves (2x2), each wave
// 4x4 frags of mfma_f32_16x16x32_bf16. global_load_lds staging; A rows are
// gathered via per-lane token addresses (global src is per-lane; LDS linear).
// Epilogue: out[tok] += w * (acc + bias) via atomicAdd (out pre-zeroed).
// ---------------------------------------------------------------------------
__global__ __launch_bounds__(256, 2)
void moe_gemm(const unsigned short* __restrict__ xb,
              const unsigned short* __restrict__ Web,
              const float* __restrict__ be, const int* __restrict__ tokl,
              const float* __restrict__ wl, const int* __restrict__ cursor,
              float* __restrict__ out) {
  __shared__ __align__(16) unsigned short As[128][32];
  __shared__ __align__(16) unsigned short Bs[128][32];  // [f][d] (B^T)
  const int bid = blockIdx.x;
  const int e  = bid >> 10;
  const int mt = (bid >> 4) & 63;
  const int nt = bid & 15;
  const int M = cursor[e * CURS_STRIDE];
  if (mt * 128 >= M) return;

  const int w = threadIdx.x >> 6, lane = threadIdx.x & 63;
  const int wr = w >> 1, wc = w & 1;

  // Staging geometry: wave w covers rows [w*32, w*32+32) of both tiles,
  // 2 glds16 each for A and B; lane l covers row +(l>>2), cols (l&3)*8..+8.
  const int rs = w * 32 + (lane >> 2);
  const int cb = (lane & 3) * 8;
  int g0 = mt * 128 + rs;      if (g0 >= M) g0 = M - 1;
  int g1 = mt * 128 + rs + 16; if (g1 >= M) g1 = M - 1;
  const unsigned short* srcA0 = xb + (size_t)tokl[e * N_TOK + g0] * D_IN + cb;
  const unsigned short* srcA1 = xb + (size_t)tokl[e * N_TOK + g1] * D_IN + cb;
  const unsigned short* srcB0 = Web + ((size_t)e * D_OUT + nt * 128 + rs) * D_IN + cb;
  const unsigned short* srcB1 = srcB0 + (size_t)16 * D_IN;
  unsigned short* ldsA0 = &As[w * 32][0];
  unsigned short* ldsA1 = &As[w * 32 + 16][0];
  unsigned short* ldsB0 = &Bs[w * 32][0];
  unsigned short* ldsB1 = &Bs[w * 32 + 16][0];

  f32x4 acc[4][4];
#pragma unroll
  for (int m = 0; m < 4; ++m)
#pragma unroll
    for (int n = 0; n < 4; ++n) acc[m][n] = (f32x4){0.f, 0.f, 0.f, 0.f};

  const int lrow = lane & 15, lk = (lane >> 4) * 8;
  const unsigned short* pA = &As[wr * 64 + lrow][lk];
  const unsigned short* pB = &Bs[wc * 64 + lrow][lk];

  for (int kk = 0; kk < D_IN / 32; ++kk) {
    glds16(srcA0 + kk * 32, ldsA0);
    glds16(srcA1 + kk * 32, ldsA1);
    glds16(srcB0 + kk * 32, ldsB0);
    glds16(srcB1 + kk * 32, ldsB1);
    __syncthreads();  // drains vmcnt -> staging visible
    s16x8 a[4], b[4];
#pragma unroll
    for (int m = 0; m < 4; ++m) a[m] = *(const s16x8*)(pA + m * 16 * 32);
#pragma unroll
    for (int n = 0; n < 4; ++n) b[n] = *(const s16x8*)(pB + n * 16 * 32);
#pragma unroll
    for (int m = 0; m < 4; ++m)
#pragma unroll
      for (int n = 0; n < 4; ++n)
        acc[m][n] = __builtin_amdgcn_mfma_f32_16x16x32_bf16(a[m], b[n], acc[m][n], 0, 0, 0);
    __syncthreads();  // all waves done reading before next overwrite
  }

  // Epilogue: C/D layout col=lane&15, row=(lane>>4)*4+q (m89-verified).
  const int colbase = nt * 128 + wc * 64 + lrow;
  float biasv[4];
#pragma unroll
  for (int n = 0; n < 4; ++n) biasv[n] = be[e * D_OUT + colbase + n * 16];
  const int rbase = mt * 128 + wr * 64 + ((lane >> 4) << 2);
#pragma unroll
  for (int m = 0; m < 4; ++m) {
#pragma unroll
    for (int q = 0; q < 4; ++q) {
      int r = rbase + m * 16 + q;
      if (r < M) {
        int tok = tokl[e * N_TOK + r];
        float wgt = wl[e * N_TOK + r];
        float* orow = out + (size_t)tok * D_OUT + colbase;
#pragma unroll
        for (int n = 0; n < 4; ++n)
          atomicAdd(orow + n * 16, wgt * (acc[m][n][q] + biasv[n]));
      }
    }
  }
}

// ---------------------------------------------------------------------------
extern "C" void kernel_launch(void* const* d_in, const int* in_sizes, int n_in,
                              void* d_out, int out_size, void* d_ws, size_t ws_size,
                              hipStream_t stream) {
  const float* x  = (const float*)d_in[0];
  const float* We = (const float*)d_in[1];
  const float* be = (const float*)d_in[2];
  const float* Wg = (const float*)d_in[3];
  const float* bg = (const float*)d_in[4];
  float* out = (float*)d_out;

  char* ws = (char*)d_ws;
  unsigned short* xb  = (unsigned short*)ws;                            // 32 MiB
  unsigned short* Web = (unsigned short*)(ws + (size_t)N_TOK * D_IN * 2); // 64 MiB
  char* meta = ws + (size_t)N_TOK * D_IN * 2 + (size_t)NEXP * D_IN * D_OUT * 2;
  int*   tokl   = (int*)meta;                                  // 256 KiB
  float* wl     = (float*)(meta + (size_t)NEXP * N_TOK * 4);   // 256 KiB
  int*   cursor = (int*)(meta + 2 * (size_t)NEXP * N_TOK * 4); // 512 B padded

  hipMemsetAsync(cursor, 0, NEXP * CURS_STRIDE * sizeof(int), stream);
  hipMemsetAsync(d_out, 0, (size_t)N_TOK * D_OUT * sizeof(float), stream);
  gate_kernel<<<N_TOK / 16, 1024, 0, stream>>>(x, Wg, bg, xb, tokl, wl, cursor);
  wconv_kernel<<<NEXP * 32 * 32, 256, 0, stream>>>(We, Web);
  moe_gemm<<<NEXP * 64 * 16, 256, 0, stream>>>(xb, Web, be, tokl, wl, cursor, out);
}

// Round 6
// 502.122 us; speedup vs baseline: 1.3744x; 1.1385x over previous
//
#include <hip/hip_runtime.h>
#include <hip/hip_bf16.h>
#include <stdint.h>

// SparseMOE: N=8192 tokens, D_in=D_out=2048, E=8, top-2.
// R5 (= R4 + route OOB fix): (1) gate reads transposed WgT (coalesced),
//     (2) atomic-free deterministic routing (single-block counting sort,
//         8 tokens/thread -- R4 had 16/thread = OOB),
//     (3) moe_gemm BK=64 + source-side XOR chunk swizzle (kills the
//         ds_read bank conflict; halves barrier count).

#define N_TOK 8192
#define D_IN  2048
#define D_OUT 2048
#define NEXP  8
#define CURS_STRIDE 16  // ints; pads each expert cursor to its own 64B line

typedef __attribute__((ext_vector_type(8))) short s16x8;   // 8 x bf16
typedef __attribute__((ext_vector_type(4))) float f32x4;

__device__ inline unsigned short f2b(float f) {
  union { float f; unsigned u; } v; v.f = f;
  unsigned u = v.u;
  return (unsigned short)((u + 0x7fffu + ((u >> 16) & 1u)) >> 16);  // RNE
}

__device__ inline void glds16(const void* g, void* l) {
  __builtin_amdgcn_global_load_lds(
      (const __attribute__((address_space(1))) unsigned int*)g,
      (__attribute__((address_space(3))) unsigned int*)l,
      16, 0, 0);
}

// ---------------------------------------------------------------------------
// Kernel 0: Wg [D_in][E] -> WgT [E][D_in] (64 KiB; enables coalesced gate).
// ---------------------------------------------------------------------------
__global__ __launch_bounds__(256)
void wgt_kernel(const float* __restrict__ Wg, float* __restrict__ WgT) {
  const int d = blockIdx.x * 256 + threadIdx.x;  // 0..2047
  const float4* src = (const float4*)(Wg + (size_t)d * NEXP);
  float4 a = src[0], b = src[1];
  WgT[0 * D_IN + d] = a.x; WgT[1 * D_IN + d] = a.y;
  WgT[2 * D_IN + d] = a.z; WgT[3 * D_IN + d] = a.w;
  WgT[4 * D_IN + d] = b.x; WgT[5 * D_IN + d] = b.y;
  WgT[6 * D_IN + d] = b.z; WgT[7 * D_IN + d] = b.w;
}

// ---------------------------------------------------------------------------
// Kernel 1: gating (fp32, exact) + x -> bf16. One wave per token. No atomics:
// writes per-token (e0,e1) and (w0,w1) records.
// ---------------------------------------------------------------------------
__global__ __launch_bounds__(256)
void gate_kernel(const float* __restrict__ x, const float* __restrict__ WgT,
                 const float* __restrict__ bg, unsigned short* __restrict__ xb,
                 int2* __restrict__ gidx, float2* __restrict__ gw) {
  const int wave = threadIdx.x >> 6, lane = threadIdx.x & 63;
  const int t = blockIdx.x * 4 + wave;
  const float4* __restrict__ xv = (const float4*)(x + (size_t)t * D_IN);
  ushort4* __restrict__ xo = (ushort4*)(xb + (size_t)t * D_IN);
  float s[NEXP] = {0.f, 0.f, 0.f, 0.f, 0.f, 0.f, 0.f, 0.f};
#pragma unroll
  for (int i = 0; i < D_IN / 256; ++i) {  // 8 float4 per lane
    const int p4 = i * 64 + lane;         // float4 index into the row
    float4 v = xv[p4];
    ushort4 o;
    o.x = f2b(v.x); o.y = f2b(v.y); o.z = f2b(v.z); o.w = f2b(v.w);
    xo[p4] = o;
#pragma unroll
    for (int e = 0; e < NEXP; ++e) {
      float4 wv = *(const float4*)(WgT + (size_t)e * D_IN + p4 * 4);
      s[e] += v.x * wv.x + v.y * wv.y + v.z * wv.z + v.w * wv.w;
    }
  }
#pragma unroll
  for (int off = 32; off > 0; off >>= 1)
#pragma unroll
    for (int e = 0; e < NEXP; ++e) s[e] += __shfl_xor(s[e], off);

  if (lane == 0) {
    float v[NEXP];
#pragma unroll
    for (int e = 0; e < NEXP; ++e) v[e] = s[e] + bg[e];
    int i0 = 0; float b0 = v[0];
#pragma unroll
    for (int e = 1; e < NEXP; ++e) if (v[e] > b0) { b0 = v[e]; i0 = e; }
    int i1 = -1; float b1 = -3.4e38f;
#pragma unroll
    for (int e = 0; e < NEXP; ++e)
      if (e != i0 && v[e] > b1) { b1 = v[e]; i1 = e; }
    float e1 = expf(b1 - b0);        // <= 1
    float inv = 1.f / (1.f + e1);
    gidx[t] = make_int2(i0, i1);
    gw[t]   = make_float2(inv, e1 * inv);  // 2-way softmax weights
  }
}

// ---------------------------------------------------------------------------
// Kernel 1b: deterministic routing. One block, 1024 threads, 8 tokens each
// (1024*8 = 8192 = N_TOK). LDS histogram + per-expert wave shfl-scan ->
// exact bases, zero atomics.
// ---------------------------------------------------------------------------
__global__ __launch_bounds__(1024)
void route_kernel(const int2* __restrict__ gidx, const float2* __restrict__ gw,
                  int* __restrict__ tokl, float* __restrict__ wl,
                  int* __restrict__ cursor) {
  __shared__ int hist[1024][9];  // pad col to break bank aliasing
  const int tid = threadIdx.x;
  int2 rec[8];
#pragma unroll
  for (int j = 0; j < 8; ++j) rec[j] = gidx[tid * 8 + j];
#pragma unroll
  for (int e = 0; e < NEXP; ++e) {
    int c = 0;
#pragma unroll
    for (int j = 0; j < 8; ++j) c += (rec[j].x == e) + (rec[j].y == e);
    hist[tid][e] = c;
  }
  __syncthreads();
  const int wv = tid >> 6, lane = tid & 63;
  if (wv < NEXP) {            // wave w scans expert w over 1024 threads
    const int e = wv;
    int carry = 0;
#pragma unroll
    for (int ch = 0; ch < 16; ++ch) {
      int v = hist[ch * 64 + lane][e];
      int incl = v;
#pragma unroll
      for (int off = 1; off < 64; off <<= 1) {
        int u = __shfl_up(incl, off);
        if (lane >= off) incl += u;
      }
      hist[ch * 64 + lane][e] = incl - v + carry;  // exclusive prefix
      carry += __shfl(incl, 63);
    }
    if (lane == 0) cursor[e * CURS_STRIDE] = carry;  // M[e]
  }
  __syncthreads();
  float2 wrec[8];
#pragma unroll
  for (int j = 0; j < 8; ++j) wrec[j] = gw[tid * 8 + j];
#pragma unroll
  for (int e = 0; e < NEXP; ++e) {   // static expert loop: no dyn reg index
    int b = hist[tid][e];
#pragma unroll
    for (int j = 0; j < 8; ++j) {
      const int t = tid * 8 + j;
      if (rec[j].x == e) { tokl[e * N_TOK + b] = t; wl[e * N_TOK + b] = wrec[j].x; ++b; }
      if (rec[j].y == e) { tokl[e * N_TOK + b] = t; wl[e * N_TOK + b] = wrec[j].y; ++b; }
    }
  }
}

// ---------------------------------------------------------------------------
// Kernel 2: We fp32 [E][K][N] -> bf16 transposed [E][N][K].
// ---------------------------------------------------------------------------
__global__ __launch_bounds__(256)
void wconv_kernel(const float* __restrict__ We, unsigned short* __restrict__ Web) {
  __shared__ unsigned short tile[64][68];
  const int b = blockIdx.x;
  const int e = b >> 10, r = (b >> 5) & 31, c = b & 31;
  const int tr = threadIdx.x >> 4, tc = threadIdx.x & 15;
  const float* src = We + ((size_t)e * 2048 + (size_t)r * 64) * 2048 + (size_t)c * 64;
#pragma unroll
  for (int i = 0; i < 4; ++i) {
    int row = tr + i * 16;
    float4 v = *(const float4*)(src + (size_t)row * 2048 + tc * 4);
    tile[tc * 4 + 0][row] = f2b(v.x);
    tile[tc * 4 + 1][row] = f2b(v.y);
    tile[tc * 4 + 2][row] = f2b(v.z);
    tile[tc * 4 + 3][row] = f2b(v.w);
  }
  __syncthreads();
  unsigned short* dst = Web + ((size_t)e * 2048 + (size_t)c * 64) * 2048 + (size_t)r * 64;
#pragma unroll
  for (int i = 0; i < 4; ++i) {
    int row = tr + i * 16;
    ushort4 o;
    o.x = tile[row][tc * 4 + 0]; o.y = tile[row][tc * 4 + 1];
    o.z = tile[row][tc * 4 + 2]; o.w = tile[row][tc * 4 + 3];
    *(ushort4*)(dst + (size_t)row * 2048 + tc * 4) = o;
  }
}

// ---------------------------------------------------------------------------
// Kernel 3: grouped expert GEMM. 128x128 tile, BK=64, 4 waves (2x2), 4x4
// frags x 2 k-halves of mfma_f32_16x16x32_bf16. Source-side XOR chunk
// swizzle (chunk ^= row&7) + swizzled ds_read => conflict-free LDS reads
// (rule #21: gload_lds dest stays linear; permute the SOURCE + the READ).
// ---------------------------------------------------------------------------
__global__ __launch_bounds__(256, 2)
void moe_gemm(const unsigned short* __restrict__ xb,
              const unsigned short* __restrict__ Web,
              const float* __restrict__ be, const int* __restrict__ tokl,
              const float* __restrict__ wl, const int* __restrict__ cursor,
              float* __restrict__ out) {
  __shared__ __align__(16) unsigned short As[128][64];
  __shared__ __align__(16) unsigned short Bs[128][64];
  const int bid = blockIdx.x;
  const int e  = bid >> 10;
  const int mt = (bid >> 4) & 63;
  const int nt = bid & 15;
  const int M = cursor[e * CURS_STRIDE];
  if (mt * 128 >= M) return;

  const int w = threadIdx.x >> 6, lane = threadIdx.x & 63;
  const int wr = w >> 1, wc = w & 1;

  // ---- staging geometry: wave w owns rows [w*32, w*32+32) of As and Bs.
  // glds #q covers 8 rows (1024 B). lane: row-in-group sr=lane>>3, chunk
  // sc=lane&7 (16B chunks). Source chunk = sc ^ (row&7) = sc ^ sr.
  const int sr = lane >> 3;
  const int sc = lane & 7;
  const int csrc = (sc ^ sr) * 8;  // element offset of swizzled source chunk
  int tk[4];
  const int arow = mt * 128 + w * 32 + sr;
#pragma unroll
  for (int q = 0; q < 4; ++q) {
    int g = arow + q * 8; if (g >= M) g = M - 1;
    tk[q] = tokl[e * N_TOK + g];
  }
  const unsigned short* srcB =
      Web + ((size_t)e * D_OUT + nt * 128 + w * 32 + sr) * D_IN + csrc;
  unsigned short* ldsA = &As[w * 32][0];
  unsigned short* ldsB = &Bs[w * 32][0];

  // ---- fragment read addresses (swizzled): global chunk c of row r lives
  // at LDS chunk c ^ (r&7). Independent of kk -> precompute pointers.
  const int lrow = lane & 15, g16 = lane >> 4;
  const unsigned short* pa[4][2];
  const unsigned short* pb[4][2];
#pragma unroll
  for (int m = 0; m < 4; ++m) {
    const int ra = wr * 64 + m * 16 + lrow;
    const int rb = wc * 64 + m * 16 + lrow;
#pragma unroll
    for (int h = 0; h < 2; ++h) {
      pa[m][h] = &As[ra][((g16 + 4 * h) ^ (ra & 7)) * 8];
      pb[m][h] = &Bs[rb][((g16 + 4 * h) ^ (rb & 7)) * 8];
    }
  }

  f32x4 acc[4][4];
#pragma unroll
  for (int m = 0; m < 4; ++m)
#pragma unroll
    for (int n = 0; n < 4; ++n) acc[m][n] = (f32x4){0.f, 0.f, 0.f, 0.f};

  for (int kk = 0; kk < D_IN / 64; ++kk) {
    const int ko = kk * 64;
#pragma unroll
    for (int q = 0; q < 4; ++q)
      glds16(xb + (size_t)tk[q] * D_IN + ko + csrc, ldsA + q * 512);
#pragma unroll
    for (int q = 0; q < 4; ++q)
      glds16(srcB + (size_t)q * 8 * D_IN + ko, ldsB + q * 512);
    __syncthreads();  // drains vmcnt -> staging visible
    s16x8 a[4][2], b[4][2];
#pragma unroll
    for (int m = 0; m < 4; ++m)
#pragma unroll
      for (int h = 0; h < 2; ++h) {
        a[m][h] = *(const s16x8*)pa[m][h];
        b[m][h] = *(const s16x8*)pb[m][h];
      }
#pragma unroll
    for (int m = 0; m < 4; ++m)
#pragma unroll
      for (int n = 0; n < 4; ++n) {
        acc[m][n] = __builtin_amdgcn_mfma_f32_16x16x32_bf16(a[m][0], b[n][0], acc[m][n], 0, 0, 0);
        acc[m][n] = __builtin_amdgcn_mfma_f32_16x16x32_bf16(a[m][1], b[n][1], acc[m][n], 0, 0, 0);
      }
    __syncthreads();  // all waves done reading before next overwrite
  }

  // Epilogue: C/D layout col=lane&15, row=(lane>>4)*4+q (m89-verified).
  const int colbase = nt * 128 + wc * 64 + lrow;
  float biasv[4];
#pragma unroll
  for (int n = 0; n < 4; ++n) biasv[n] = be[e * D_OUT + colbase + n * 16];
  const int rbase = mt * 128 + wr * 64 + (g16 << 2);
#pragma unroll
  for (int m = 0; m < 4; ++m) {
#pragma unroll
    for (int q = 0; q < 4; ++q) {
      int r = rbase + m * 16 + q;
      if (r < M) {
        int tok = tokl[e * N_TOK + r];
        float wgt = wl[e * N_TOK + r];
        float* orow = out + (size_t)tok * D_OUT + colbase;
#pragma unroll
        for (int n = 0; n < 4; ++n)
          atomicAdd(orow + n * 16, wgt * (acc[m][n][q] + biasv[n]));
      }
    }
  }
}

// ---------------------------------------------------------------------------
extern "C" void kernel_launch(void* const* d_in, const int* in_sizes, int n_in,
                              void* d_out, int out_size, void* d_ws, size_t ws_size,
                              hipStream_t stream) {
  const float* x  = (const float*)d_in[0];
  const float* We = (const float*)d_in[1];
  const float* be = (const float*)d_in[2];
  const float* Wg = (const float*)d_in[3];
  const float* bg = (const float*)d_in[4];
  float* out = (float*)d_out;

  char* ws = (char*)d_ws;
  unsigned short* xb  = (unsigned short*)ws;                              // 32 MiB
  unsigned short* Web = (unsigned short*)(ws + (size_t)N_TOK * D_IN * 2); // 64 MiB
  char* meta = ws + (size_t)N_TOK * D_IN * 2 + (size_t)NEXP * D_IN * D_OUT * 2;
  int*    tokl   = (int*)meta;                                   // 256 KiB
  float*  wl     = (float*)(meta + (size_t)NEXP * N_TOK * 4);    // 256 KiB
  int*    cursor = (int*)(meta + 2 * (size_t)NEXP * N_TOK * 4);  // 512 B
  float*  WgT    = (float*)(meta + 2 * (size_t)NEXP * N_TOK * 4 + 4096);
  int2*   gidx   = (int2*)((char*)WgT + (size_t)NEXP * D_IN * 4);   // 64 KiB
  float2* gw     = (float2*)((char*)gidx + (size_t)N_TOK * 8);      // 64 KiB

  hipMemsetAsync(d_out, 0, (size_t)N_TOK * D_OUT * sizeof(float), stream);
  wgt_kernel<<<D_IN / 256, 256, 0, stream>>>(Wg, WgT);
  gate_kernel<<<N_TOK / 4, 256, 0, stream>>>(x, WgT, bg, xb, gidx, gw);
  route_kernel<<<1, 1024, 0, stream>>>(gidx, gw, tokl, wl, cursor);
  wconv_kernel<<<NEXP * 32 * 32, 256, 0, stream>>>(We, Web);
  moe_gemm<<<NEXP * 64 * 16, 256, 0, stream>>>(xb, Web, be, tokl, wl, cursor, out);
}